// Round 10
// baseline (123.284 us; speedup 1.0000x reference)
//
#include <hip/hip_runtime.h>
#include <hip/hip_bf16.h>
#include <math.h>

#define EPS 1e-6f
#define NLAYERS 63
#define SINK_ITERS 20
#define LOG2E 1.4426950408889634f

typedef __attribute__((ext_vector_type(8))) short bf16x8;      // 8 bf16 = 4 VGPRs
typedef __attribute__((ext_vector_type(4))) float f32x4;       // MFMA C/D
typedef __attribute__((ext_vector_type(4))) unsigned int ui32x4;

__device__ __forceinline__ float fast_log2(float v) {
#if __has_builtin(__builtin_amdgcn_logf)
  return __builtin_amdgcn_logf(v);
#else
  return log2f(v);
#endif
}
__device__ __forceinline__ float fast_exp2(float v) {
#if __has_builtin(__builtin_amdgcn_exp2f)
  return __builtin_amdgcn_exp2f(v);
#else
  return exp2f(v);
#endif
}

// fp32 -> bf16 RNE (bit pattern).
__device__ __forceinline__ unsigned int f2bf(float f) {
  unsigned int u = __float_as_uint(f);
  return (u + 0x7FFFu + ((u >> 16) & 1u)) >> 16;
}

// Packed HW convert: 2 f32 -> 2 bf16 in one instruction (RNE on gfx950).
__device__ __forceinline__ unsigned int cvt_pk_bf16(float lo, float hi) {
  unsigned int r;
  asm("v_cvt_pk_bf16_f32 %0, %1, %2" : "=v"(r) : "v"(lo), "v"(hi));
  return r;
}
// Union-free pack: ext-vector lane writes stay in SSA registers (no scratch).
__device__ __forceinline__ bf16x8 pack8(float4 a, float4 b) {
  ui32x4 u;
  u[0] = cvt_pk_bf16(a.x, a.y);
  u[1] = cvt_pk_bf16(a.z, a.w);
  u[2] = cvt_pk_bf16(b.x, b.y);
  u[3] = cvt_pk_bf16(b.z, b.w);
  return __builtin_bit_cast(bf16x8, u);
}

// ---------------------------------------------------------------------------
// R23: scan with 2 rows/thread + software prefetch.
// R22 analysis: 4096 waves = 16/CU in ONE residency round -> at t=0 every
// wave issues its whole 256B x-gather (256 KB/CU in flight), the memory
// system drains it SERIALLY before any compute (~10 us), then the chain runs
// with HBM idle. Fix: 512 rows/block (grid 512, 2 blocks/CU, 8 waves/CU at
// (256,2) -> VGPR cap 256, no demotion). Pass-B's 16 dwordx4 loads are
// issued right after pass-A's first GEMM; the raw float4[4][4] (64 VGPR,
// static idx) stays in flight under pass-A's ~4000-cy chain. Half the x
// traffic hidden, t=0 burst halved.
//  k1 (1 block): 4-wave sinkhorn (R18+ verified) -> Pfrag + layer consts.
//  k2: barrier-free scan, wave-local Lv, template chunks, s_load consts.
//
// Layer encoding [63][8]: {sgn, e1, lcg, cw1 | Sc, Oc, e0, cw0} (R15):
//   cr = clamp(r); xr = Sc*cr + Oc; g = exp2(e0*log2(xr) + e1*log2(yr) + lcg);
//   r' = cw0*xr + cw1*yr + g.   Final: out = sgn_62*r + off_62.
// ---------------------------------------------------------------------------

__global__ __launch_bounds__(256) void sinkhorn_kernel(
    const float* __restrict__ logits,
    const float* __restrict__ weights,
    const float* __restrict__ biases,
    unsigned short* __restrict__ Pfrag,  // [8][64][8] bf16
    float* __restrict__ layers) {        // [63][8]
  __shared__ float T[64 * 65];
  __shared__ float Uv[64];
  __shared__ float Vv[64];
  __shared__ float part[256];

  const int tid = threadIdx.x;
  const int w = tid >> 6, l = tid & 63;   // w is wave-uniform
  const int q = l >> 4, c = l & 15;

  // ---- Layer constants (independent of sinkhorn) -> global.
  if (tid < NLAYERS) {
    float w0 = weights[tid];
    float w1 = 1.0f - w0;
    float a  = biases[tid];
    float sgn, e0, e1, cw0, cw1, lcg;
    if (fabsf(a - 0.5f) < EPS) {
      sgn = 1.f; e0 = 0.f; e1 = 0.f; cw0 = w0; cw1 = w1; lcg = -1.0e30f;
    } else {
      float ae;
      if (a < 0.5f) { sgn = -1.f; ae = fminf(fmaxf(1.0f - a, -1.0f + EPS), 2.0f - EPS); }
      else          { sgn =  1.f; ae = a; }
      float pp = sqrtf(3.0f / fmaxf(2.0f - ae, EPS)) - 1.0f;
      float cl, cg;
      if (ae >= 0.75f) { cl = 0.0f;            cg = 1.0f; }
      else             { cl = 3.0f - 4.0f*ae;  cg = 4.0f*ae - 2.0f; }
      e0  = 2.0f * w0 * pp;
      e1  = 2.0f * w1 * pp;
      cw0 = cl * w0;
      cw1 = cl * w1;
      lcg = (cg > 0.f) ? log2f(cg) : -1.0e30f;
    }
    float sgnp = 1.f;
    if (tid > 0) {
      float ap = biases[tid - 1];
      sgnp = (fabsf(ap - 0.5f) < EPS) ? 1.f : (ap < 0.5f ? -1.f : 1.f);
    }
    float Sc = sgn * sgnp;
    float Oc = 0.5f - 0.5f * Sc;
    float* Lr = layers + tid * 8;
    Lr[0] = sgn; Lr[1] = e1; Lr[2] = lcg; Lr[3] = cw1;
    Lr[4] = Sc;  Lr[5] = Oc; Lr[6] = e0;  Lr[7] = cw0;
  }

  // ---- 4-wave Sinkhorn (verified R18-R22). Thread (w,l):
  // K_part[i] = K[l][16w+i], KT_part[i] = K[16w+i][l] (16+16 regs).
  float K_part[16], KT_part[16];
  {
    const float4* lr = (const float4*)(logits + (l << 6) + (w << 4));
    #pragma unroll
    for (int i = 0; i < 4; ++i) {
      float4 t = lr[i];
      K_part[4*i+0] = fast_exp2(t.x * LOG2E);
      K_part[4*i+1] = fast_exp2(t.y * LOG2E);
      K_part[4*i+2] = fast_exp2(t.z * LOG2E);
      K_part[4*i+3] = fast_exp2(t.w * LOG2E);
    }
  }
  #pragma unroll
  for (int i = 0; i < 16; ++i) T[l * 65 + (w << 4) + i] = K_part[i];
  if (tid < 64) Vv[tid] = 1.0f;
  __syncthreads();
  #pragma unroll
  for (int i = 0; i < 16; ++i) KT_part[i] = T[((w << 4) + i) * 65 + l];

  for (int it = 0; it < SINK_ITERS; ++it) {
    float p0 = 0.f, p1 = 0.f, p2 = 0.f, p3 = 0.f;
    #pragma unroll
    for (int i = 0; i < 4; ++i) {
      p0 = fmaf(K_part[4*i+0], Vv[(w << 4) + 4*i+0], p0);   // broadcast reads
      p1 = fmaf(K_part[4*i+1], Vv[(w << 4) + 4*i+1], p1);
      p2 = fmaf(K_part[4*i+2], Vv[(w << 4) + 4*i+2], p2);
      p3 = fmaf(K_part[4*i+3], Vv[(w << 4) + 4*i+3], p3);
    }
    part[(w << 6) + l] = (p0 + p1) + (p2 + p3);
    __syncthreads();
    if (tid < 64) {
      float s = (part[tid] + part[64 + tid]) + (part[128 + tid] + part[192 + tid]);
      Uv[tid] = 1.0f / s;
    }
    __syncthreads();
    float q0 = 0.f, q1 = 0.f, q2 = 0.f, q3 = 0.f;
    #pragma unroll
    for (int i = 0; i < 4; ++i) {
      q0 = fmaf(KT_part[4*i+0], Uv[(w << 4) + 4*i+0], q0);
      q1 = fmaf(KT_part[4*i+1], Uv[(w << 4) + 4*i+1], q1);
      q2 = fmaf(KT_part[4*i+2], Uv[(w << 4) + 4*i+2], q2);
      q3 = fmaf(KT_part[4*i+3], Uv[(w << 4) + 4*i+3], q3);
    }
    part[(w << 6) + l] = (q0 + q1) + (q2 + q3);
    __syncthreads();
    if (tid < 64) {
      float s = (part[tid] + part[64 + tid]) + (part[128 + tid] + part[192 + tid]);
      Vv[tid] = 1.0f / s;
    }
    __syncthreads();
  }

  // ---- P = diag(u) K diag(v) -> T.
  {
    const float ul = Uv[l];
    #pragma unroll
    for (int i = 0; i < 16; ++i)
      T[l * 65 + (w << 4) + i] = ul * K_part[i] * Vv[(w << 4) + i];
  }
  __syncthreads();

  // ---- Fragment store (wave w handles fragments 2w, 2w+1): lane l holds
  // B[k][n], k = s*32 + q*8 + j, n = t*16 + c (validated layout R6-R22).
  #pragma unroll
  for (int fi = 0; fi < 2; ++fi) {
    const int f = (w << 1) + fi;         // 0..7
    const int s = f >> 2, t = f & 3;
    ui32x4 u;
    #pragma unroll
    for (int jj = 0; jj < 4; ++jj) {
      unsigned int lo = f2bf(T[(s*32 + (q << 3) + 2*jj    ) * 65 + t*16 + c]);
      unsigned int hi = f2bf(T[(s*32 + (q << 3) + 2*jj + 1) * 65 + t*16 + c]);
      u[jj] = lo | (hi << 16);
    }
    *(ui32x4*)(Pfrag + ((f * 64 + l) << 3)) = u;   // coalesced 16B stores
  }
}

// ---------------------------------------------------------------------------

template<int HALF>
__device__ __forceinline__ void do_gemm(const bf16x8 (&Bf)[2][4],
                                        const bf16x8 (&Af)[4][2],
                                        float* Lv, int w, int q, int c) {
  #pragma unroll
  for (int rt = 0; rt < 4; ++rt) {
    #pragma unroll
    for (int lt = 0; lt < 2; ++lt) {
      f32x4 acc = {0.f, 0.f, 0.f, 0.f};
      acc = __builtin_amdgcn_mfma_f32_16x16x32_bf16(Bf[0][(HALF << 1) + lt], Af[rt][0], acc, 0, 0, 0);
      acc = __builtin_amdgcn_mfma_f32_16x16x32_bf16(Bf[1][(HALF << 1) + lt], Af[rt][1], acc, 0, 0, 0);
      const int row  = (w << 6) + (rt << 4) + c;   // block-local batch row
      const int nloc = (lt << 4) + (q << 2);       // local leaf col 0..28
      *(f32x4*)&Lv[row * 36 + nloc] = acc;         // ds_write_b128 (wave-local)
    }
  }
}

// One 8-step chunk, L0 compile-time. Layer consts via Lp4 (global, wave-
// uniform address -> s_load_dwordx4, SGPR operands). Leaf n pairs with
// layer n-1.
template<int L0>
__device__ __forceinline__ void do_chunk(const float* Lrow,
                                         const float4* Lp4, float& r) {
  constexpr int loc = L0 & 31;
  f32x4 lf0 = *(const f32x4*)&Lrow[loc];
  f32x4 lf1 = *(const f32x4*)&Lrow[loc + 4];
  float lf[8] = {lf0[0], lf0[1], lf0[2], lf0[3], lf1[0], lf1[1], lf1[2], lf1[3]};

  float ylin[8], ylg[8];
  #pragma unroll
  for (int k = 0; k < 8; ++k) {
    if (L0 + k >= 1) {                              // compile-time fold
      float4 p0 = Lp4[(L0 + k - 1) * 2];            // {sgn, e1, lcg, cw1}
      float off = fmaf(-0.5f, p0.x, 0.5f);
      float yy  = fminf(fmaxf(lf[k], EPS), 1.0f - EPS);
      float yr  = fmaf(p0.x, yy, off);
      float ly  = fast_log2(yr);
      ylg[k]  = fmaf(p0.y, ly, p0.z);               // e1*log2(yr) + log2(cg)
      ylin[k] = p0.w * yr;                          // cl*w1*yr
    }
  }

  // Dependent chain, 6 ops on the critical path:
  //   med3 -> fma(reflect) -> log -> fma -> exp -> add  (lin fma parallel)
  #pragma unroll
  for (int k = 0; k < 8; ++k) {
    if (L0 + k >= 1) {
      float4 p1 = Lp4[(L0 + k - 1) * 2 + 1];        // {Sc, Oc, e0, cw0}
      float cr = fminf(fmaxf(r, EPS), 1.0f - EPS);  // v_med3_f32
      float xr = fmaf(p1.x, cr, p1.y);              // composed reflect
      float lx = fast_log2(xr);
      float g  = fast_exp2(fmaf(p1.z, lx, ylg[k])); // cg * x'^e0 * y'^e1
      r = fmaf(p1.w, xr, ylin[k]) + g;              // cl*lin + cg*g
    } else {
      r = lf[0];                                    // state_0 = leaf_0
    }
  }
}

// One 256-row pass: GEMM^T both halves + 63-step scan + store.
__device__ __forceinline__ void run_pass(const bf16x8 (&Bf)[2][4],
                                         const bf16x8 (&Af)[4][2],
                                         float* Lv, const float4* Lp4,
                                         const float* __restrict__ layers,
                                         float* __restrict__ out,
                                         size_t rowbase, int tid,
                                         int w, int q, int c) {
  const float* Lrow = &Lv[tid * 36];
  float r = 0.f;

  do_gemm<0>(Bf, Af, Lv, w, q, c);
  do_chunk<0>(Lrow, Lp4, r);
  do_chunk<8>(Lrow, Lp4, r);
  do_chunk<16>(Lrow, Lp4, r);
  do_chunk<24>(Lrow, Lp4, r);

  // Wave-local DS ordering makes the Lv overwrite safe: this wave's half-0
  // reads precede these writes in program order, and rows 64w..64w+63 are
  // read only by wave w.
  do_gemm<1>(Bf, Af, Lv, w, q, c);
  do_chunk<32>(Lrow, Lp4, r);
  do_chunk<40>(Lrow, Lp4, r);
  do_chunk<48>(Lrow, Lp4, r);
  do_chunk<56>(Lrow, Lp4, r);

  const float sgnL = layers[62 * 8];
  out[rowbase + tid] = fmaf(sgnL, r, fmaf(-0.5f, sgnL, 0.5f));
}

__global__ __launch_bounds__(256, 2) void scan_kernel(
    const float* __restrict__ x,
    const unsigned short* __restrict__ Pfrag,
    const float* __restrict__ layers,
    float* __restrict__ out) {
  __shared__ float Lv[256 * 36];                    // 36864 B
  const int tid = threadIdx.x;
  const int w = tid >> 6, l = tid & 63;
  const int q = l >> 4, c = l & 15;
  const size_t rowbase = (size_t)blockIdx.x << 9;   // 512 rows per block
  const float4* Lp4 = (const float4*)layers;        // uniform -> s_load

  const float* rpA = x + (rowbase + (w << 6) + c) * 64 + (q << 3);
  const float* rpB = rpA + 256 * 64;

  #define LOADROW(dst, base, i) do {                               \
    const float* rp = (base) + ((i) << 4) * 64;                    \
    (dst)[0] = *(const float4*)(rp);                               \
    (dst)[1] = *(const float4*)(rp + 4);                           \
    (dst)[2] = *(const float4*)(rp + 32);                          \
    (dst)[3] = *(const float4*)(rp + 36);                          \
  } while (0)

  // ---- Pass-A loads + pack (double-buffered staging, transient 32 VGPR).
  bf16x8 AfA[4][2];
  {
    float4 t0[4], t1[4];
    LOADROW(t0, rpA, 0);
    LOADROW(t1, rpA, 1);
    AfA[0][0] = pack8(t0[0], t0[1]); AfA[0][1] = pack8(t0[2], t0[3]);
    LOADROW(t0, rpA, 2);
    AfA[1][0] = pack8(t1[0], t1[1]); AfA[1][1] = pack8(t1[2], t1[3]);
    LOADROW(t1, rpA, 3);
    AfA[2][0] = pack8(t0[0], t0[1]); AfA[2][1] = pack8(t0[2], t0[3]);
    AfA[3][0] = pack8(t1[0], t1[1]); AfA[3][1] = pack8(t1[2], t1[3]);
  }

  // ---- B fragments: 8 x 16B coalesced loads from L2-hot Pfrag.
  bf16x8 Bf[2][4];
  #pragma unroll
  for (int s = 0; s < 2; ++s)
    #pragma unroll
    for (int t = 0; t < 4; ++t)
      Bf[s][t] = *(const bf16x8*)(Pfrag + (((s*4 + t) * 64 + l) << 3));

  // ---- Pass A GEMM half 0, then PREFETCH pass-B rows: the 16 dwordx4
  // loads (dest xb[4][4], 64 VGPR, static idx) stay in flight under the
  // ~4000-cycle pass-A chain; first use (pack) is after pass-A completes.
  const float* LrowA = &Lv[tid * 36];
  float rA = 0.f;

  do_gemm<0>(Bf, AfA, Lv, w, q, c);

  float4 xb[4][4];
  #pragma unroll
  for (int i = 0; i < 4; ++i)
    LOADROW(xb[i], rpB, i);
  #undef LOADROW

  do_chunk<0>(LrowA, Lp4, rA);
  do_chunk<8>(LrowA, Lp4, rA);
  do_chunk<16>(LrowA, Lp4, rA);
  do_chunk<24>(LrowA, Lp4, rA);
  do_gemm<1>(Bf, AfA, Lv, w, q, c);   // AfA dies after this
  do_chunk<32>(LrowA, Lp4, rA);
  do_chunk<40>(LrowA, Lp4, rA);
  do_chunk<48>(LrowA, Lp4, rA);
  do_chunk<56>(LrowA, Lp4, rA);

  const float sgnL = layers[62 * 8];
  out[rowbase + tid] = fmaf(sgnL, rA, fmaf(-0.5f, sgnL, 0.5f));

  // ---- Pass B: pack (loads have long since landed), GEMM + scan.
  bf16x8 AfB[4][2];
  #pragma unroll
  for (int i = 0; i < 4; ++i) {
    AfB[i][0] = pack8(xb[i][0], xb[i][1]);
    AfB[i][1] = pack8(xb[i][2], xb[i][3]);
  }
  run_pass(Bf, AfB, Lv, Lp4, layers, out, rowbase + 256, tid, w, q, c);
}

// ---------------------------------------------------------------------------
extern "C" void kernel_launch(void* const* d_in, const int* in_sizes, int n_in,
                              void* d_out, int out_size, void* d_ws, size_t ws_size,
                              hipStream_t stream) {
  const float* x       = (const float*)d_in[0];
  const float* logits  = (const float*)d_in[1];
  const float* weights = (const float*)d_in[2];
  const float* biases  = (const float*)d_in[3];
  float* out = (float*)d_out;

  unsigned short* Pfrag = (unsigned short*)d_ws;              // 8 KB
  float* layers = (float*)((char*)d_ws + 8 * 64 * 8 * sizeof(unsigned short));

  const int batch = out_size;  // 262144

  hipLaunchKernelGGL(sinkhorn_kernel, dim3(1), dim3(256), 0, stream,
                     logits, weights, biases, Pfrag, layers);
  hipLaunchKernelGGL(scan_kernel, dim3(batch / 512), dim3(256), 0, stream,
                     x, Pfrag, layers, out);
}

// Round 11
// 115.152 us; speedup vs baseline: 1.0706x; 1.0706x over previous
//
#include <hip/hip_runtime.h>
#include <hip/hip_bf16.h>
#include <math.h>

#define EPS 1e-6f
#define NLAYERS 63
#define SINK_ITERS 20
#define LOG2E 1.4426950408889634f

typedef __attribute__((ext_vector_type(8))) short bf16x8;      // 8 bf16 = 4 VGPRs
typedef __attribute__((ext_vector_type(4))) float f32x4;       // MFMA C/D
typedef __attribute__((ext_vector_type(4))) unsigned int ui32x4;

__device__ __forceinline__ float fast_log2(float v) {
#if __has_builtin(__builtin_amdgcn_logf)
  return __builtin_amdgcn_logf(v);
#else
  return log2f(v);
#endif
}
__device__ __forceinline__ float fast_exp2(float v) {
#if __has_builtin(__builtin_amdgcn_exp2f)
  return __builtin_amdgcn_exp2f(v);
#else
  return exp2f(v);
#endif
}

// fp32 -> bf16 RNE (bit pattern).
__device__ __forceinline__ unsigned int f2bf(float f) {
  unsigned int u = __float_as_uint(f);
  return (u + 0x7FFFu + ((u >> 16) & 1u)) >> 16;
}

// Packed HW convert: 2 f32 -> 2 bf16 in one instruction (RNE on gfx950).
__device__ __forceinline__ unsigned int cvt_pk_bf16(float lo, float hi) {
  unsigned int r;
  asm("v_cvt_pk_bf16_f32 %0, %1, %2" : "=v"(r) : "v"(lo), "v"(hi));
  return r;
}
// Union-free pack: ext-vector lane writes stay in SSA registers (no scratch).
__device__ __forceinline__ bf16x8 pack8(float4 a, float4 b) {
  ui32x4 u;
  u[0] = cvt_pk_bf16(a.x, a.y);
  u[1] = cvt_pk_bf16(a.z, a.w);
  u[2] = cvt_pk_bf16(b.x, b.y);
  u[3] = cvt_pk_bf16(b.z, b.w);
  return __builtin_bit_cast(bf16x8, u);
}

// ---------------------------------------------------------------------------
// R24 = R22 verbatim (verified best, 115.6 us). R23's 2-rows/thread prefetch
// regressed (123.3): it halved waves/CU (16 -> 8), and the lost TLP in the
// chain phase outweighed the hidden memory latency. The problem's total
// parallelism is fixed at rows/64 = 4096 waves = 16 waves/CU at 1 row/thread;
// R22 sits at that optimum with VGPR 52 (<128 cap) and LDS 36.9 KB
// (4 blocks/CU).
//  k1 (1 block, 256 thr): 4-wave sinkhorn (spill-free) -> Pfrag (bf16 MFMA
//     B-fragments, wave-split coalesced stores) + layer consts.
//  k2 (1024 blocks, 256 thr, (256,4)): scan only, barrier-free (wave-local
//     Lv), template chunks, s_load layer consts.
//
// Layer encoding [63][8]: {sgn, e1, lcg, cw1 | Sc, Oc, e0, cw0} (R15):
//   cr = clamp(r); xr = Sc*cr + Oc; g = exp2(e0*log2(xr) + e1*log2(yr) + lcg);
//   r' = cw0*xr + cw1*yr + g.   Final: out = sgn_62*r + off_62.
// ---------------------------------------------------------------------------

__global__ __launch_bounds__(256) void sinkhorn_kernel(
    const float* __restrict__ logits,
    const float* __restrict__ weights,
    const float* __restrict__ biases,
    unsigned short* __restrict__ Pfrag,  // [8][64][8] bf16
    float* __restrict__ layers) {        // [63][8]
  __shared__ float T[64 * 65];
  __shared__ float Uv[64];
  __shared__ float Vv[64];
  __shared__ float part[256];

  const int tid = threadIdx.x;
  const int w = tid >> 6, l = tid & 63;   // w is wave-uniform
  const int q = l >> 4, c = l & 15;

  // ---- Layer constants (independent of sinkhorn) -> global.
  if (tid < NLAYERS) {
    float w0 = weights[tid];
    float w1 = 1.0f - w0;
    float a  = biases[tid];
    float sgn, e0, e1, cw0, cw1, lcg;
    if (fabsf(a - 0.5f) < EPS) {
      sgn = 1.f; e0 = 0.f; e1 = 0.f; cw0 = w0; cw1 = w1; lcg = -1.0e30f;
    } else {
      float ae;
      if (a < 0.5f) { sgn = -1.f; ae = fminf(fmaxf(1.0f - a, -1.0f + EPS), 2.0f - EPS); }
      else          { sgn =  1.f; ae = a; }
      float pp = sqrtf(3.0f / fmaxf(2.0f - ae, EPS)) - 1.0f;
      float cl, cg;
      if (ae >= 0.75f) { cl = 0.0f;            cg = 1.0f; }
      else             { cl = 3.0f - 4.0f*ae;  cg = 4.0f*ae - 2.0f; }
      e0  = 2.0f * w0 * pp;
      e1  = 2.0f * w1 * pp;
      cw0 = cl * w0;
      cw1 = cl * w1;
      lcg = (cg > 0.f) ? log2f(cg) : -1.0e30f;
    }
    float sgnp = 1.f;
    if (tid > 0) {
      float ap = biases[tid - 1];
      sgnp = (fabsf(ap - 0.5f) < EPS) ? 1.f : (ap < 0.5f ? -1.f : 1.f);
    }
    float Sc = sgn * sgnp;
    float Oc = 0.5f - 0.5f * Sc;
    float* Lr = layers + tid * 8;
    Lr[0] = sgn; Lr[1] = e1; Lr[2] = lcg; Lr[3] = cw1;
    Lr[4] = Sc;  Lr[5] = Oc; Lr[6] = e0;  Lr[7] = cw0;
  }

  // ---- 4-wave Sinkhorn (verified R18-R22). Thread (w,l):
  // K_part[i] = K[l][16w+i], KT_part[i] = K[16w+i][l] (16+16 regs).
  float K_part[16], KT_part[16];
  {
    const float4* lr = (const float4*)(logits + (l << 6) + (w << 4));
    #pragma unroll
    for (int i = 0; i < 4; ++i) {
      float4 t = lr[i];
      K_part[4*i+0] = fast_exp2(t.x * LOG2E);
      K_part[4*i+1] = fast_exp2(t.y * LOG2E);
      K_part[4*i+2] = fast_exp2(t.z * LOG2E);
      K_part[4*i+3] = fast_exp2(t.w * LOG2E);
    }
  }
  #pragma unroll
  for (int i = 0; i < 16; ++i) T[l * 65 + (w << 4) + i] = K_part[i];
  if (tid < 64) Vv[tid] = 1.0f;
  __syncthreads();
  #pragma unroll
  for (int i = 0; i < 16; ++i) KT_part[i] = T[((w << 4) + i) * 65 + l];

  for (int it = 0; it < SINK_ITERS; ++it) {
    float p0 = 0.f, p1 = 0.f, p2 = 0.f, p3 = 0.f;
    #pragma unroll
    for (int i = 0; i < 4; ++i) {
      p0 = fmaf(K_part[4*i+0], Vv[(w << 4) + 4*i+0], p0);   // broadcast reads
      p1 = fmaf(K_part[4*i+1], Vv[(w << 4) + 4*i+1], p1);
      p2 = fmaf(K_part[4*i+2], Vv[(w << 4) + 4*i+2], p2);
      p3 = fmaf(K_part[4*i+3], Vv[(w << 4) + 4*i+3], p3);
    }
    part[(w << 6) + l] = (p0 + p1) + (p2 + p3);
    __syncthreads();
    if (tid < 64) {
      float s = (part[tid] + part[64 + tid]) + (part[128 + tid] + part[192 + tid]);
      Uv[tid] = 1.0f / s;
    }
    __syncthreads();
    float q0 = 0.f, q1 = 0.f, q2 = 0.f, q3 = 0.f;
    #pragma unroll
    for (int i = 0; i < 4; ++i) {
      q0 = fmaf(KT_part[4*i+0], Uv[(w << 4) + 4*i+0], q0);
      q1 = fmaf(KT_part[4*i+1], Uv[(w << 4) + 4*i+1], q1);
      q2 = fmaf(KT_part[4*i+2], Uv[(w << 4) + 4*i+2], q2);
      q3 = fmaf(KT_part[4*i+3], Uv[(w << 4) + 4*i+3], q3);
    }
    part[(w << 6) + l] = (q0 + q1) + (q2 + q3);
    __syncthreads();
    if (tid < 64) {
      float s = (part[tid] + part[64 + tid]) + (part[128 + tid] + part[192 + tid]);
      Vv[tid] = 1.0f / s;
    }
    __syncthreads();
  }

  // ---- P = diag(u) K diag(v) -> T.
  {
    const float ul = Uv[l];
    #pragma unroll
    for (int i = 0; i < 16; ++i)
      T[l * 65 + (w << 4) + i] = ul * K_part[i] * Vv[(w << 4) + i];
  }
  __syncthreads();

  // ---- Fragment store (wave w handles fragments 2w, 2w+1): lane l holds
  // B[k][n], k = s*32 + q*8 + j, n = t*16 + c (validated layout R6-R23).
  #pragma unroll
  for (int fi = 0; fi < 2; ++fi) {
    const int f = (w << 1) + fi;         // 0..7
    const int s = f >> 2, t = f & 3;
    ui32x4 u;
    #pragma unroll
    for (int jj = 0; jj < 4; ++jj) {
      unsigned int lo = f2bf(T[(s*32 + (q << 3) + 2*jj    ) * 65 + t*16 + c]);
      unsigned int hi = f2bf(T[(s*32 + (q << 3) + 2*jj + 1) * 65 + t*16 + c]);
      u[jj] = lo | (hi << 16);
    }
    *(ui32x4*)(Pfrag + ((f * 64 + l) << 3)) = u;   // coalesced 16B stores
  }
}

// ---------------------------------------------------------------------------

template<int HALF>
__device__ __forceinline__ void do_gemm(const bf16x8 (&Bf)[2][4],
                                        const bf16x8 (&Af)[4][2],
                                        float* Lv, int w, int q, int c) {
  #pragma unroll
  for (int rt = 0; rt < 4; ++rt) {
    #pragma unroll
    for (int lt = 0; lt < 2; ++lt) {
      f32x4 acc = {0.f, 0.f, 0.f, 0.f};
      acc = __builtin_amdgcn_mfma_f32_16x16x32_bf16(Bf[0][(HALF << 1) + lt], Af[rt][0], acc, 0, 0, 0);
      acc = __builtin_amdgcn_mfma_f32_16x16x32_bf16(Bf[1][(HALF << 1) + lt], Af[rt][1], acc, 0, 0, 0);
      const int row  = (w << 6) + (rt << 4) + c;   // block-local batch row
      const int nloc = (lt << 4) + (q << 2);       // local leaf col 0..28
      *(f32x4*)&Lv[row * 36 + nloc] = acc;         // ds_write_b128 (wave-local)
    }
  }
}

// One 8-step chunk, L0 compile-time. Layer consts via Lp4 (global, wave-
// uniform address -> s_load_dwordx4, SGPR operands). Leaf n pairs with
// layer n-1.
template<int L0>
__device__ __forceinline__ void do_chunk(const float* Lrow,
                                         const float4* Lp4, float& r) {
  constexpr int loc = L0 & 31;
  f32x4 lf0 = *(const f32x4*)&Lrow[loc];
  f32x4 lf1 = *(const f32x4*)&Lrow[loc + 4];
  float lf[8] = {lf0[0], lf0[1], lf0[2], lf0[3], lf1[0], lf1[1], lf1[2], lf1[3]};

  float ylin[8], ylg[8];
  #pragma unroll
  for (int k = 0; k < 8; ++k) {
    if (L0 + k >= 1) {                              // compile-time fold
      float4 p0 = Lp4[(L0 + k - 1) * 2];            // {sgn, e1, lcg, cw1}
      float off = fmaf(-0.5f, p0.x, 0.5f);
      float yy  = fminf(fmaxf(lf[k], EPS), 1.0f - EPS);
      float yr  = fmaf(p0.x, yy, off);
      float ly  = fast_log2(yr);
      ylg[k]  = fmaf(p0.y, ly, p0.z);               // e1*log2(yr) + log2(cg)
      ylin[k] = p0.w * yr;                          // cl*w1*yr
    }
  }

  // Dependent chain, 6 ops on the critical path:
  //   med3 -> fma(reflect) -> log -> fma -> exp -> add  (lin fma parallel)
  #pragma unroll
  for (int k = 0; k < 8; ++k) {
    if (L0 + k >= 1) {
      float4 p1 = Lp4[(L0 + k - 1) * 2 + 1];        // {Sc, Oc, e0, cw0}
      float cr = fminf(fmaxf(r, EPS), 1.0f - EPS);  // v_med3_f32
      float xr = fmaf(p1.x, cr, p1.y);              // composed reflect
      float lx = fast_log2(xr);
      float g  = fast_exp2(fmaf(p1.z, lx, ylg[k])); // cg * x'^e0 * y'^e1
      r = fmaf(p1.w, xr, ylin[k]) + g;              // cl*lin + cg*g
    } else {
      r = lf[0];                                    // state_0 = leaf_0
    }
  }
}

__global__ __launch_bounds__(256, 4) void scan_kernel(
    const float* __restrict__ x,
    const unsigned short* __restrict__ Pfrag,
    const float* __restrict__ layers,
    float* __restrict__ out) {
  __shared__ float Lv[256 * 36];                    // 36864 B -> 4 blocks/CU
  const int tid = threadIdx.x;
  const int w = tid >> 6, l = tid & 63;
  const int q = l >> 4, c = l & 15;
  const size_t rowbase = (size_t)blockIdx.x << 8;   // 256 rows per block
  const float4* Lp4 = (const float4*)layers;        // uniform -> s_load

  // ---- A fragments: double-buffered load + union-free pack.
  bf16x8 Af[4][2];
  {
    const float* rp0 = x + (rowbase + (w << 6) + c) * 64 + (q << 3);
    float4 t0[4], t1[4];
    #define LOADROW(dst, i) do {                                   \
      const float* rp = rp0 + ((i) << 4) * 64;                     \
      (dst)[0] = *(const float4*)(rp);                             \
      (dst)[1] = *(const float4*)(rp + 4);                         \
      (dst)[2] = *(const float4*)(rp + 32);                        \
      (dst)[3] = *(const float4*)(rp + 36);                        \
    } while (0)
    LOADROW(t0, 0);
    LOADROW(t1, 1);
    Af[0][0] = pack8(t0[0], t0[1]); Af[0][1] = pack8(t0[2], t0[3]);
    LOADROW(t0, 2);
    Af[1][0] = pack8(t1[0], t1[1]); Af[1][1] = pack8(t1[2], t1[3]);
    LOADROW(t1, 3);
    Af[2][0] = pack8(t0[0], t0[1]); Af[2][1] = pack8(t0[2], t0[3]);
    Af[3][0] = pack8(t1[0], t1[1]); Af[3][1] = pack8(t1[2], t1[3]);
    #undef LOADROW
  }

  // ---- B fragments: 8 x 16B coalesced loads from L2-hot Pfrag.
  bf16x8 Bf[2][4];
  #pragma unroll
  for (int s = 0; s < 2; ++s)
    #pragma unroll
    for (int t = 0; t < 4; ++t)
      Bf[s][t] = *(const bf16x8*)(Pfrag + (((s*4 + t) * 64 + l) << 3));

  // ---- GEMM^T + 63-step scan. Barrier-free: each wave writes/reads only
  // its own 64 Lv rows (wave-local DS ordering, validated R6-R23).
  const float* Lrow = &Lv[tid * 36];
  float r = 0.f;

  do_gemm<0>(Bf, Af, Lv, w, q, c);
  do_chunk<0>(Lrow, Lp4, r);
  do_chunk<8>(Lrow, Lp4, r);
  do_chunk<16>(Lrow, Lp4, r);
  do_chunk<24>(Lrow, Lp4, r);

  do_gemm<1>(Bf, Af, Lv, w, q, c);
  do_chunk<32>(Lrow, Lp4, r);
  do_chunk<40>(Lrow, Lp4, r);
  do_chunk<48>(Lrow, Lp4, r);
  do_chunk<56>(Lrow, Lp4, r);

  // ---- final unreflect of the last layer.
  const float sgnL = layers[62 * 8];
  out[rowbase + tid] = fmaf(sgnL, r, fmaf(-0.5f, sgnL, 0.5f));
}

// ---------------------------------------------------------------------------
extern "C" void kernel_launch(void* const* d_in, const int* in_sizes, int n_in,
                              void* d_out, int out_size, void* d_ws, size_t ws_size,
                              hipStream_t stream) {
  const float* x       = (const float*)d_in[0];
  const float* logits  = (const float*)d_in[1];
  const float* weights = (const float*)d_in[2];
  const float* biases  = (const float*)d_in[3];
  float* out = (float*)d_out;

  unsigned short* Pfrag = (unsigned short*)d_ws;              // 8 KB
  float* layers = (float*)((char*)d_ws + 8 * 64 * 8 * sizeof(unsigned short));

  const int batch = out_size;  // 262144

  hipLaunchKernelGGL(sinkhorn_kernel, dim3(1), dim3(256), 0, stream,
                     logits, weights, biases, Pfrag, layers);
  hipLaunchKernelGGL(scan_kernel, dim3(batch / 256), dim3(256), 0, stream,
                     x, Pfrag, layers, out);
}